// Round 1
// baseline (174.434 us; speedup 1.0000x reference)
//
#include <hip/hip_runtime.h>

typedef float f32x4 __attribute__((ext_vector_type(4)));
typedef short bf16x8 __attribute__((ext_vector_type(8)));

#define AS1 __attribute__((address_space(1)))
#define AS3 __attribute__((address_space(3)))

__device__ __forceinline__ void gl16(const void* g, void* l) {
  __builtin_amdgcn_global_load_lds((const AS1 unsigned int*)g,
                                   (AS3 unsigned int*)l, 16, 0, 0);
}

__device__ __forceinline__ unsigned short f2bf(float f) {
  unsigned u = __float_as_uint(f);
  u = u + 0x7FFFu + ((u >> 16) & 1u);   // RNE
  return (unsigned short)(u >> 16);
}

// ---------------- K1: style = s @ style_weight^T + style_bias  [N=4, Cin=64]
__global__ __launch_bounds__(256) void k_style(const float* __restrict__ s,
                                               const float* __restrict__ sw,
                                               const float* __restrict__ sb,
                                               float* __restrict__ style) {
  int t = threadIdx.x;
  int n = t >> 6, i = t & 63;
  float acc = sb[i];
  const float* sp = s + n * 512;
  const float* wp = sw + i * 512;
  for (int k = 0; k < 512; ++k) acc += sp[k] * wp[k];
  style[t] = acc;  // t == n*64 + i
}

// ---------------- K2: modulate + demodulate -> bf16, layout wm[(n*27+k)*64+o][i]
// row = 128B, chunk(16B) XOR-swizzled by (o&7) so linear global_load_lds +
// swizzled ds_read_b128 is bank-conflict-free.
__global__ __launch_bounds__(256) void k_wmod(const float* __restrict__ weight,
                                              const float* __restrict__ style,
                                              unsigned short* __restrict__ wm) {
  int o = blockIdx.x, n = blockIdx.y, t = threadIdx.x;
  int lane = t & 63, wv = t >> 6;
  const float* wp = weight + o * 1728;   // [i][27]
  const float* st = style + n * 64;
  float v[7];
  float ss = 0.f;
#pragma unroll
  for (int j = 0; j < 7; ++j) {
    int idx = t + j * 256;
    float w = 0.f;
    if (idx < 1728) {
      int i = idx / 27;
      w = wp[idx] * st[i];
    }
    v[j] = w;
    ss += w * w;
  }
#pragma unroll
  for (int off = 32; off > 0; off >>= 1) ss += __shfl_down(ss, off);
  __shared__ float red[4];
  if (lane == 0) red[wv] = ss;
  __syncthreads();
  float total = red[0] + red[1] + red[2] + red[3];
  float dm = 1.0f / sqrtf(total + 1e-8f);
#pragma unroll
  for (int j = 0; j < 7; ++j) {
    int idx = t + j * 256;
    if (idx < 1728) {
      int i = idx / 27, k = idx - i * 27;
      int g = (n * 27 + k) * 64 + o;
      wm[g * 64 + (((i >> 3) ^ (o & 7)) << 3) + (i & 7)] = f2bf(v[j] * dm);
    }
  }
}

// ---------------- K3: x[N][64][48^3] fp32 -> xT[(n*110592+p)][i] bf16,
// 16B chunks XOR-swizzled by (p&7). 128p x 64i tile per block via LDS.
__global__ __launch_bounds__(256) void k_xpose(const float* __restrict__ x,
                                               unsigned short* __restrict__ xT) {
  __shared__ unsigned tile[128][33];
  int n = blockIdx.y;
  int p0 = blockIdx.x * 128;
  int t = threadIdx.x;
  int wv = t >> 6, lane = t & 63;
  const float* xb = x + (size_t)n * 64 * 110592 + p0;
#pragma unroll
  for (int c = 0; c < 8; ++c) {
    int i2 = c * 4 + wv;      // pair index 0..31
    int i = i2 * 2;
    int pl = lane * 2;
    const float* r0 = xb + (size_t)i * 110592 + pl;
    const float* r1 = r0 + 110592;
    float2 a = *(const float2*)r0;
    float2 b = *(const float2*)r1;
    tile[pl][i2]     = (unsigned)f2bf(a.x) | ((unsigned)f2bf(b.x) << 16);
    tile[pl + 1][i2] = (unsigned)f2bf(a.y) | ((unsigned)f2bf(b.y) << 16);
  }
  __syncthreads();
  uint4* dst = (uint4*)xT;
#pragma unroll
  for (int c = 0; c < 4; ++c) {
    int pl = (t >> 3) + c * 32;
    int r = t & 7;  // chunk index (8 i's)
    uint4 u;
    u.x = tile[pl][r * 4 + 0];
    u.y = tile[pl][r * 4 + 1];
    u.z = tile[pl][r * 4 + 2];
    u.w = tile[pl][r * 4 + 3];
    int R = n * 110592 + p0 + pl;
    dst[(size_t)R * 8 + (r ^ (pl & 7))] = u;   // p0 % 8 == 0 -> key = pl&7
  }
}

// ---------------- K4: implicit-GEMM conv. Block: n, 256 flat positions, o=64.
// 4 waves; wave tile = 64o x 64pos -> per K-32 step 4 A-frags + 4 B-frags -> 16 MFMA.
__global__ __launch_bounds__(256) void k_conv(const unsigned short* __restrict__ xT,
                                              const unsigned short* __restrict__ wm,
                                              const float* __restrict__ bias,
                                              float* __restrict__ out) {
  __shared__ uint4 smem4[(46080 + 8192) / 16];
  char* Bl = (char*)smem4;            // 360 rows x 128B B slab
  char* Al = (char*)smem4 + 46080;    // 64 rows x 128B A slice
  int n = blockIdx.y;
  int p0 = blockIdx.x * 256;
  int t = threadIdx.x;
  int lane = t & 63, wv = t >> 6;
  int l15 = lane & 15, lhi = lane >> 4;
  f32x4 acc[4][4] = {};

  const char* xb = (const char*)xT + ((size_t)(n * 110592 + p0)) * 128;
  const char* wb = (const char*)wm + (size_t)n * 27 * 8192;

  for (int kd = 0; kd < 3; ++kd) {
    __syncthreads();  // prior reads of Bl done
    const char* src = xb + (size_t)kd * (2304 * 128);
    for (int cc = wv; cc < 45; cc += 4)
      gl16(src + cc * 1024 + lane * 16, Bl + cc * 1024);
    for (int kh = 0; kh < 3; ++kh)
      for (int kw = 0; kw < 3; ++kw) {
        int sidx = (kd * 3 + kh) * 3 + kw;
        __syncthreads();  // drains B staging (1st iter) / prior A reads
        const char* asrc = wb + (size_t)sidx * 8192;
        gl16(asrc + wv * 1024 + lane * 16, Al + wv * 1024);
        gl16(asrc + (wv + 4) * 1024 + lane * 16, Al + (wv + 4) * 1024);
        __syncthreads();  // A (and B) ready
        int rbase = wv * 64 + kh * 48 + kw;
#pragma unroll
        for (int ih = 0; ih < 2; ++ih) {
          int c = lhi + ih * 4;  // unswizzled 16B-chunk index (i-range)
          bf16x8 a[4], b[4];
#pragma unroll
          for (int m = 0; m < 4; ++m) {
            int orow = m * 16 + l15;
            a[m] = *(const bf16x8*)(Al + orow * 128 + ((c ^ (orow & 7)) << 4));
          }
#pragma unroll
          for (int q = 0; q < 4; ++q) {
            int r = rbase + q * 16 + l15;
            b[q] = *(const bf16x8*)(Bl + r * 128 + ((c ^ (r & 7)) << 4));
          }
#pragma unroll
          for (int m = 0; m < 4; ++m)
#pragma unroll
            for (int q = 0; q < 4; ++q)
              acc[m][q] = __builtin_amdgcn_mfma_f32_16x16x32_bf16(a[m], b[q], acc[m][q], 0, 0, 0);
        }
      }
  }

  float bv[4][4];
#pragma unroll
  for (int m = 0; m < 4; ++m)
#pragma unroll
    for (int r = 0; r < 4; ++r) bv[m][r] = bias[m * 16 + lhi * 4 + r];

  float* ob = out + (size_t)n * 64 * 97336;
#pragma unroll
  for (int q = 0; q < 4; ++q) {
    int p = p0 + wv * 64 + q * 16 + l15;
    int d = p / 2304;
    int rem = p - d * 2304;
    int h = rem / 48;
    int w = rem - h * 48;
    if (h < 46 && w < 46) {  // d < 46 guaranteed: p <= 105983
      int base = d * 2116 + h * 46 + w;
#pragma unroll
      for (int m = 0; m < 4; ++m)
#pragma unroll
        for (int r = 0; r < 4; ++r) {
          int o = m * 16 + lhi * 4 + r;
          ob[(size_t)o * 97336 + base] = acc[m][q][r] + bv[m][r];
        }
    }
  }
}

extern "C" void kernel_launch(void* const* d_in, const int* in_sizes, int n_in,
                              void* d_out, int out_size, void* d_ws, size_t ws_size,
                              hipStream_t stream) {
  const float* x    = (const float*)d_in[0];
  const float* s    = (const float*)d_in[1];
  const float* sw   = (const float*)d_in[2];
  const float* sb   = (const float*)d_in[3];
  const float* wt   = (const float*)d_in[4];
  const float* bias = (const float*)d_in[5];
  float* out = (float*)d_out;

  // ws layout: [0,1024) style fp32; [1024, 885760) wm bf16 (4*27*64*64);
  // [885760, +57,225,472) xT bf16 incl. 4706-row tail pad for shift overreach.
  float* style          = (float*)d_ws;
  unsigned short* wm    = (unsigned short*)((char*)d_ws + 1024);
  unsigned short* xT    = (unsigned short*)((char*)d_ws + 1024 + 884736);

  hipLaunchKernelGGL(k_style, dim3(1), dim3(256), 0, stream, s, sw, sb, style);
  hipLaunchKernelGGL(k_wmod, dim3(64, 4), dim3(256), 0, stream, wt, style, wm);
  hipLaunchKernelGGL(k_xpose, dim3(864, 4), dim3(256), 0, stream, x, xT);
  hipLaunchKernelGGL(k_conv, dim3(414, 4), dim3(256), 0, stream, xT, wm, bias, out);
}